// Round 4
// baseline (560.844 us; speedup 1.0000x reference)
//
#include <hip/hip_runtime.h>

#define NB   16
#define SQL  2048
#define SKL  2048
#define DKL  64
#define DVL  64
#define NE   (NB * SQL * DKL)   /* 2,097,152 elems per tensor */

typedef __attribute__((ext_vector_type(8))) short short8;
typedef __attribute__((ext_vector_type(4))) short s16x4;
typedef __attribute__((ext_vector_type(4))) float f32x4;
typedef __attribute__((ext_vector_type(4))) int   i32x4;
typedef __attribute__((ext_vector_type(4))) unsigned u32x4;

#define SCALE_LOG2E 0.1803368801111204f  /* (1/sqrt(64)) * log2(e) */
#define EXP2F(x) __builtin_amdgcn_exp2f(x)
#define MFMA32(a,b,c) __builtin_amdgcn_mfma_f32_16x16x32_bf16((a),(b),(c),0,0,0)

__device__ __forceinline__ short f2bf(float x) {  // rne f32 -> bf16 bits
    unsigned u = __builtin_bit_cast(unsigned, x);
    u = (u + 0x7fffu + ((u >> 16) & 1u)) >> 16;
    return (short)u;
}
__device__ __forceinline__ float bf2f(short s) {
    return __builtin_bit_cast(float, ((unsigned)(unsigned short)s) << 16);
}

// pack 8 f32 -> 8 bf16 (RNE) via v_cvt_pk_bf16_f32 (no builtin exists; asm per T12)
__device__ __forceinline__ short8 pk8(f32x4 a, f32x4 b) {
    unsigned w0, w1, w2, w3;
    asm("v_cvt_pk_bf16_f32 %0, %1, %2" : "=v"(w0) : "v"(a[0]), "v"(a[1]));
    asm("v_cvt_pk_bf16_f32 %0, %1, %2" : "=v"(w1) : "v"(a[2]), "v"(a[3]));
    asm("v_cvt_pk_bf16_f32 %0, %1, %2" : "=v"(w2) : "v"(b[0]), "v"(b[1]));
    asm("v_cvt_pk_bf16_f32 %0, %1, %2" : "=v"(w3) : "v"(b[2]), "v"(b[3]));
    u32x4 t = {w0, w1, w2, w3};
    return __builtin_bit_cast(short8, t);
}

// ---------- prep: split Q,K into bf16 hi/lo ----------
__global__ __launch_bounds__(256)
void prep(const float* __restrict__ Q, const float* __restrict__ K,
          short* __restrict__ ws)
{
    short* qhi = ws;
    short* qlo = ws + (size_t)NE;
    short* khi = ws + (size_t)2 * NE;
    short* klo = ws + (size_t)3 * NE;

    size_t i4 = ((size_t)blockIdx.x * 256 + threadIdx.x) * 4;
    if (i4 >= NE) return;

    f32x4 q = *(const f32x4*)(Q + i4);
    f32x4 k = *(const f32x4*)(K + i4);
    s16x4 qh, ql, kh, kl;
    #pragma unroll
    for (int j = 0; j < 4; j++) {
        qh[j] = f2bf(q[j]);  ql[j] = f2bf(q[j] - bf2f(qh[j]));
        kh[j] = f2bf(k[j]);  kl[j] = f2bf(k[j] - bf2f(kh[j]));
    }
    *(s16x4*)(qhi + i4) = qh;
    *(s16x4*)(qlo + i4) = ql;
    *(s16x4*)(khi + i4) = kh;
    *(s16x4*)(klo + i4) = kl;
}

// ---------- vtrans: V fp32 [b][k][v] -> bf16 Vt, MFMA-slot-tiled ----------
// Vt[v][t*32 + quad*8 + jj] = V[key][v] with
//   key = t*32 + quad*4 + (jj&3) + 16*(jj>>2)
// matching the packed-P A-fragment slot order, so ONE mfma_16x16x32 per
// v-tile computes the full 32-key PV contribution.
__global__ __launch_bounds__(256)
void vtrans(const float* __restrict__ V, short* __restrict__ vt)
{
    __shared__ short st[64][72];          // 64x64 tile, padded stride
    const int b  = blockIdx.x >> 5;       // 32 k-tiles (of 64) per batch
    const int kt = blockIdx.x & 31;
    const int t  = threadIdx.x;

    const int kr = t >> 2;                // 0..63  (k row within tile)
    const int c0 = (t & 3) * 16;          // v col chunk
    const float* vsrc = V + ((size_t)(b * SKL) + kt * 64 + kr) * DVL + c0;
    #pragma unroll
    for (int j = 0; j < 4; j++) {
        f32x4 x = *(const f32x4*)(vsrc + j * 4);
        #pragma unroll
        for (int i = 0; i < 4; i++) st[kr][c0 + j * 4 + i] = f2bf(x[i]);
    }
    __syncthreads();

    const int vr = t >> 2;                // v row of output
    const int cc = (t & 3) * 16;          // 16-elem chunk within 64 keys
    short* dst = vt + (size_t)b * DVL * SKL + (size_t)vr * SKL + kt * 64 + cc;
    short o[16];
    #pragma unroll
    for (int m = 0; m < 16; m++) {
        int kk = cc + m;
        int tb = kk >> 5;
        int w5 = kk & 31;
        int qd = w5 >> 3;
        int jj = w5 & 7;
        int kl = tb * 32 + qd * 4 + (jj & 3) + ((jj >> 2) << 4);
        o[m] = st[kl][vr];
    }
    *(short8*)(dst)     = *(short8*)(o);
    *(short8*)(dst + 8) = *(short8*)(o + 8);
}

// Block = one 16-row q-tile, 4 waves each owning a 512-key quarter (K-split).
// Swapped QK: S^T = mfma(K_frag, Q_frag) -> lane holds P[q=l15][key=quad*4+r],
// i.e. P is lane-local: no LDS round-trip, no in-loop barriers, coalesced
// dwordx4 attn stores (CACHED, not NT: NT stores retire at HBM and serialize
// the shared in-order vmcnt pipe -> every iter paid a ~1us store round-trip).
__global__ __launch_bounds__(256, 4)
void attn_fwd(const short* __restrict__ ws, const int* __restrict__ mask,
              float* __restrict__ out, float* __restrict__ attn)
{
    __shared__ __align__(16) char smem[16384 + 256];
    f32x4* s_acc = (f32x4*)smem;                 // vt-major: [vt][w*64+lane] (16 KB)
    float* s_red = (float*)(smem + 16384);       // 4 waves x 16 row-sums

    const int tid  = threadIdx.x;
    const int w    = tid >> 6;                   // wave = k-quarter
    const int lane = tid & 63;
    const int l15  = tid & 15;
    const int quad = (tid & 63) >> 4;

    // bijective XCD swizzle: 2048 blocks, 256-block chunks per XCD
    const int bid = blockIdx.x;
    const int swz = (bid & 7) * ((NB * SQL / 16) >> 3) + (bid >> 3);
    const int b     = swz >> 7;
    const int qbase = (swz & 127) * 16;

    const int k0 = w * (SKL / 4);
    const int k1 = k0 + SKL / 4;

    const short* qhi = ws + (size_t)(b * SQL + qbase) * DKL;
    const short* qlo = qhi + (size_t)NE;
    const short* khi = ws + (size_t)2 * NE + (size_t)b * SKL * DKL;
    const short* klo = khi + (size_t)NE;
    const short* vtg = ws + (size_t)4 * NE + (size_t)b * DVL * SKL;
    const int*   mk  = mask + b * SKL;

    // Q fragments (B-operand of swapped QK: lane l15 = q, quad = d-chunk)
    short8 qa0h = *(const short8*)(qhi + (size_t)l15 * DKL + quad * 8);
    short8 qa1h = *(const short8*)(qhi + (size_t)l15 * DKL + 32 + quad * 8);
    short8 qa0l = *(const short8*)(qlo + (size_t)l15 * DKL + quad * 8);
    short8 qa1l = *(const short8*)(qlo + (size_t)l15 * DKL + 32 + quad * 8);

    // ---------- sweep 1: partial denominators over this wave's quarter ----------
    float lsum = 0.f;
    for (int kb = k0; kb < k1; kb += 32) {
        size_t o0 = (size_t)(kb + l15) * DKL + quad * 8;
        size_t o1 = o0 + (size_t)16 * DKL;
        short8 h0l = *(const short8*)(khi + o0);
        short8 h0h = *(const short8*)(khi + o0 + 32);
        short8 h1l = *(const short8*)(khi + o1);
        short8 h1h = *(const short8*)(khi + o1 + 32);
        short8 l0l = *(const short8*)(klo + o0);
        short8 l0h = *(const short8*)(klo + o0 + 32);
        short8 l1l = *(const short8*)(klo + o1);
        short8 l1h = *(const short8*)(klo + o1 + 32);
        i32x4 m0 = *(const i32x4*)(mk + kb + quad * 4);
        i32x4 m1 = *(const i32x4*)(mk + kb + 16 + quad * 4);

        f32x4 z = {0.f, 0.f, 0.f, 0.f};
        f32x4 sA0 = MFMA32(h0l, qa0h, z);
        sA0 = MFMA32(l0l, qa0h, sA0);
        sA0 = MFMA32(h0l, qa0l, sA0);
        f32x4 sB0 = MFMA32(h0h, qa1h, z);
        sB0 = MFMA32(l0h, qa1h, sB0);
        sB0 = MFMA32(h0h, qa1l, sB0);
        f32x4 sA1 = MFMA32(h1l, qa0h, z);
        sA1 = MFMA32(l1l, qa0h, sA1);
        sA1 = MFMA32(h1l, qa0l, sA1);
        f32x4 sB1 = MFMA32(h1h, qa1h, z);
        sB1 = MFMA32(l1h, qa1h, sB1);
        sB1 = MFMA32(h1h, qa1l, sB1);

        #pragma unroll
        for (int r = 0; r < 4; r++) {
            lsum += EXP2F(fmaf(sA0[r] + sB0[r], SCALE_LOG2E, m0[r] ? 0.f : -1e9f));
            lsum += EXP2F(fmaf(sA1[r] + sB1[r], SCALE_LOG2E, m1[r] ? 0.f : -1e9f));
        }
    }
    lsum += __shfl_xor(lsum, 16, 64);
    lsum += __shfl_xor(lsum, 32, 64);
    if (lane < 16) s_red[w * 16 + l15] = lsum;
    __syncthreads();
    const float tot  = s_red[l15] + s_red[16 + l15] + s_red[32 + l15] + s_red[48 + l15];
    const float lg2i = -__log2f(tot);   // fold 1/sum into the exp2 argument

    // ---------- sweep 2: attn write + partial P·V ----------
    f32x4 acc[4];
    #pragma unroll
    for (int vt = 0; vt < 4; vt++) { f32x4 z = {0.f,0.f,0.f,0.f}; acc[vt] = z; }

    for (int kb = k0; kb < k1; kb += 32) {
        // V fragments: one coalesced 16B load per 16-v tile (MFMA-slot-tiled Vt)
        const short* vrow = vtg + kb + quad * 8;
        short8 vv0 = *(const short8*)(vrow + (size_t)(0 * 16 + l15) * SKL);
        short8 vv1 = *(const short8*)(vrow + (size_t)(1 * 16 + l15) * SKL);
        short8 vv2 = *(const short8*)(vrow + (size_t)(2 * 16 + l15) * SKL);
        short8 vv3 = *(const short8*)(vrow + (size_t)(3 * 16 + l15) * SKL);
        i32x4 m0 = *(const i32x4*)(mk + kb + quad * 4);
        i32x4 m1 = *(const i32x4*)(mk + kb + 16 + quad * 4);

        size_t o0 = (size_t)(kb + l15) * DKL + quad * 8;
        size_t o1 = o0 + (size_t)16 * DKL;
        short8 h0l = *(const short8*)(khi + o0);
        short8 h0h = *(const short8*)(khi + o0 + 32);
        short8 h1l = *(const short8*)(khi + o1);
        short8 h1h = *(const short8*)(khi + o1 + 32);
        short8 l0l = *(const short8*)(klo + o0);
        short8 l0h = *(const short8*)(klo + o0 + 32);
        short8 l1l = *(const short8*)(klo + o1);
        short8 l1h = *(const short8*)(klo + o1 + 32);

        f32x4 z = {0.f, 0.f, 0.f, 0.f};
        f32x4 sA0 = MFMA32(h0l, qa0h, z);
        sA0 = MFMA32(l0l, qa0h, sA0);
        sA0 = MFMA32(h0l, qa0l, sA0);
        f32x4 sB0 = MFMA32(h0h, qa1h, z);
        sB0 = MFMA32(l0h, qa1h, sB0);
        sB0 = MFMA32(h0h, qa1l, sB0);
        f32x4 sA1 = MFMA32(h1l, qa0h, z);
        sA1 = MFMA32(l1l, qa0h, sA1);
        sA1 = MFMA32(h1l, qa0l, sA1);
        f32x4 sB1 = MFMA32(h1h, qa1h, z);
        sB1 = MFMA32(l1h, qa1h, sB1);
        sB1 = MFMA32(h1h, qa1l, sB1);

        // normalized probabilities: exp2(s*scale + (mask ? -log2(sum) : -1e9))
        f32x4 p0, p1;
        #pragma unroll
        for (int r = 0; r < 4; r++) {
            p0[r] = EXP2F(fmaf(sA0[r] + sB0[r], SCALE_LOG2E, m0[r] ? lg2i : -1e9f));
            p1[r] = EXP2F(fmaf(sA1[r] + sB1[r], SCALE_LOG2E, m1[r] ? lg2i : -1e9f));
        }

        // attn stores: two coalesced dwordx4 per lane, CACHED (retire at L2)
        float* arow = attn + (size_t)(b * SQL + qbase + l15) * SKL + kb + quad * 4;
        *(f32x4*)arow        = p0;
        *(f32x4*)(arow + 16) = p1;

        // packed P [p0|p1] is the mfma_16x16x32 A-fragment matching Vt's slots
        short8 pa = pk8(p0, p1);
        acc[0] = MFMA32(pa, vv0, acc[0]);
        acc[1] = MFMA32(pa, vv1, acc[1]);
        acc[2] = MFMA32(pa, vv2, acc[2]);
        acc[3] = MFMA32(pa, vv3, acc[3]);
    }

    // ---------- combine partial P·V across the 4 k-quarter waves ----------
    // vt-major layout: writes and reads are 1KB-dense per wave (2 lanes/bank, free)
    #pragma unroll
    for (int vt = 0; vt < 4; vt++) s_acc[vt * 256 + w * 64 + lane] = acc[vt];
    __syncthreads();

    f32x4 t_ = s_acc[w * 256 + 0 * 64 + lane];
    #pragma unroll
    for (int wp = 1; wp < 4; wp++) {
        f32x4 u = s_acc[w * 256 + wp * 64 + lane];
        #pragma unroll
        for (int r = 0; r < 4; r++) t_[r] += u[r];
    }
    #pragma unroll
    for (int r = 0; r < 4; r++)
        out[(size_t)(b * SQL + qbase + quad * 4 + r) * DVL + w * 16 + l15] = t_[r];
}

extern "C" void kernel_launch(void* const* d_in, const int* in_sizes, int n_in,
                              void* d_out, int out_size, void* d_ws, size_t ws_size,
                              hipStream_t stream) {
    const float* Q    = (const float*)d_in[0];
    const float* K    = (const float*)d_in[1];
    const float* V    = (const float*)d_in[2];
    const int*   mask = (const int*)d_in[3];
    float* out  = (float*)d_out;
    float* attn = out + (size_t)NB * SQL * DVL;  // tuple order: (output, attn)
    short* ws   = (short*)d_ws;                  // 5*NE shorts = 20 MB

    prep<<<dim3(NE / (256 * 4)), dim3(256), 0, stream>>>(Q, K, ws);
    vtrans<<<dim3(NB * (SKL / 64)), dim3(256), 0, stream>>>(V, ws + (size_t)4 * NE);
    attn_fwd<<<dim3(NB * (SQL / 16)), dim3(256), 0, stream>>>(ws, mask, out, attn);
}

// Round 6
// 525.837 us; speedup vs baseline: 1.0666x; 1.0666x over previous
//
#include <hip/hip_runtime.h>

#define NB   16
#define SQL  2048
#define SKL  2048
#define DKL  64
#define DVL  64
#define NE   (NB * SQL * DKL)   /* 2,097,152 elems per tensor */

typedef __attribute__((ext_vector_type(8))) short short8;
typedef __attribute__((ext_vector_type(4))) short s16x4;
typedef __attribute__((ext_vector_type(4))) float f32x4;
typedef __attribute__((ext_vector_type(4))) int   i32x4;
typedef __attribute__((ext_vector_type(4))) unsigned u32x4;

#define SCALE_LOG2E 0.1803368801111204f  /* (1/sqrt(64)) * log2(e) */
#define EXP2F(x) __builtin_amdgcn_exp2f(x)
#define MFMA32(a,b,c) __builtin_amdgcn_mfma_f32_16x16x32_bf16((a),(b),(c),0,0,0)

__device__ __forceinline__ short f2bf(float x) {  // rne f32 -> bf16 bits
    unsigned u = __builtin_bit_cast(unsigned, x);
    u = (u + 0x7fffu + ((u >> 16) & 1u)) >> 16;
    return (short)u;
}
__device__ __forceinline__ float bf2f(short s) {
    return __builtin_bit_cast(float, ((unsigned)(unsigned short)s) << 16);
}

// pack 8 f32 -> 8 bf16 (RNE) via v_cvt_pk_bf16_f32
__device__ __forceinline__ short8 pk8(f32x4 a, f32x4 b) {
    unsigned w0, w1, w2, w3;
    asm("v_cvt_pk_bf16_f32 %0, %1, %2" : "=v"(w0) : "v"(a[0]), "v"(a[1]));
    asm("v_cvt_pk_bf16_f32 %0, %1, %2" : "=v"(w1) : "v"(a[2]), "v"(a[3]));
    asm("v_cvt_pk_bf16_f32 %0, %1, %2" : "=v"(w2) : "v"(b[0]), "v"(b[1]));
    asm("v_cvt_pk_bf16_f32 %0, %1, %2" : "=v"(w3) : "v"(b[2]), "v"(b[3]));
    u32x4 t = {w0, w1, w2, w3};
    return __builtin_bit_cast(short8, t);
}

// ---------- prep: split Q,K into bf16 hi/lo ----------
__global__ __launch_bounds__(256)
void prep(const float* __restrict__ Q, const float* __restrict__ K,
          short* __restrict__ ws)
{
    short* qhi = ws;
    short* qlo = ws + (size_t)NE;
    short* khi = ws + (size_t)2 * NE;
    short* klo = ws + (size_t)3 * NE;

    size_t i4 = ((size_t)blockIdx.x * 256 + threadIdx.x) * 4;
    if (i4 >= NE) return;

    f32x4 q = *(const f32x4*)(Q + i4);
    f32x4 k = *(const f32x4*)(K + i4);
    s16x4 qh, ql, kh, kl;
    #pragma unroll
    for (int j = 0; j < 4; j++) {
        qh[j] = f2bf(q[j]);  ql[j] = f2bf(q[j] - bf2f(qh[j]));
        kh[j] = f2bf(k[j]);  kl[j] = f2bf(k[j] - bf2f(kh[j]));
    }
    *(s16x4*)(qhi + i4) = qh;
    *(s16x4*)(qlo + i4) = ql;
    *(s16x4*)(khi + i4) = kh;
    *(s16x4*)(klo + i4) = kl;
}

// ---------- vtrans: V fp32 [b][k][v] -> bf16 Vt, MFMA-slot-tiled ----------
// Vt[v][t*32 + quad*8 + jj] = V[t*32 + quad*4 + (jj&3) + 16*(jj>>2)][v]
// so a 16B load at (v*SKL + kb + quad*8) is the B-fragment matching the
// packed-P A-fragment slot order: ONE mfma_16x16x32 per v-tile per 32 keys.
__global__ __launch_bounds__(256)
void vtrans(const float* __restrict__ V, short* __restrict__ vt)
{
    __shared__ short st[64][72];          // 64x64 tile, padded stride
    const int b  = blockIdx.x >> 5;       // 32 k-tiles (of 64) per batch
    const int kt = blockIdx.x & 31;
    const int t  = threadIdx.x;

    const int kr = t >> 2;                // 0..63  (k row within tile)
    const int c0 = (t & 3) * 16;          // v col chunk
    const float* vsrc = V + ((size_t)(b * SKL) + kt * 64 + kr) * DVL + c0;
    #pragma unroll
    for (int j = 0; j < 4; j++) {
        f32x4 x = *(const f32x4*)(vsrc + j * 4);
        #pragma unroll
        for (int i = 0; i < 4; i++) st[kr][c0 + j * 4 + i] = f2bf(x[i]);
    }
    __syncthreads();

    const int vr = t >> 2;                // v row of output
    const int cc = (t & 3) * 16;          // 16-elem chunk within 64 keys
    short* dst = vt + (size_t)b * DVL * SKL + (size_t)vr * SKL + kt * 64 + cc;
    short o[16];
    #pragma unroll
    for (int m = 0; m < 16; m++) {
        int kk = cc + m;
        int tb = kk >> 5;
        int w5 = kk & 31;
        int qd = w5 >> 3;
        int jj = w5 & 7;
        int kl = tb * 32 + qd * 4 + (jj & 3) + ((jj >> 2) << 4);
        o[m] = st[kl][vr];
    }
    *(short8*)(dst)     = *(short8*)(o);
    *(short8*)(dst + 8) = *(short8*)(o + 8);
}

// load the 8 K hi/lo tiles for a 32-key block into register set P
#define LOADK(P, kb) {                                                  \
    size_t o0 = (size_t)((kb) + l15) * DKL + quad * 8;                  \
    size_t o1 = o0 + (size_t)16 * DKL;                                  \
    P##h0l = *(const short8*)(khi + o0);                                \
    P##h0h = *(const short8*)(khi + o0 + 32);                           \
    P##h1l = *(const short8*)(khi + o1);                                \
    P##h1h = *(const short8*)(khi + o1 + 32);                           \
    P##l0l = *(const short8*)(klo + o0);                                \
    P##l0h = *(const short8*)(klo + o0 + 32);                           \
    P##l1l = *(const short8*)(klo + o1);                                \
    P##l1h = *(const short8*)(klo + o1 + 32);                           \
}

#define LOADV(kb) {                                                     \
    const short* vrow = vtg + (kb) + quad * 8;                          \
    Vv0 = *(const short8*)(vrow + (size_t)(0 * 16 + l15) * SKL);        \
    Vv1 = *(const short8*)(vrow + (size_t)(1 * 16 + l15) * SKL);        \
    Vv2 = *(const short8*)(vrow + (size_t)(2 * 16 + l15) * SKL);        \
    Vv3 = *(const short8*)(vrow + (size_t)(3 * 16 + l15) * SKL);        \
}

// one 32-key step: QK (split-bf16), unnormalized P' = exp2(s*scale + bias),
// accumulate lsum + PV, store P' fp32 to attn (normalized later by `norm`)
#define STEP(P, kb) {                                                   \
    i32x4 m0 = *(const i32x4*)(mk + (kb) + quad * 4);                   \
    i32x4 m1 = *(const i32x4*)(mk + (kb) + 16 + quad * 4);              \
    f32x4 z = {0.f, 0.f, 0.f, 0.f};                                     \
    f32x4 sA0 = MFMA32(P##h0l, qa0h, z);                                \
    sA0 = MFMA32(P##l0l, qa0h, sA0);                                    \
    sA0 = MFMA32(P##h0l, qa0l, sA0);                                    \
    f32x4 sB0 = MFMA32(P##h0h, qa1h, z);                                \
    sB0 = MFMA32(P##l0h, qa1h, sB0);                                    \
    sB0 = MFMA32(P##h0h, qa1l, sB0);                                    \
    f32x4 sA1 = MFMA32(P##h1l, qa0h, z);                                \
    sA1 = MFMA32(P##l1l, qa0h, sA1);                                    \
    sA1 = MFMA32(P##h1l, qa0l, sA1);                                    \
    f32x4 sB1 = MFMA32(P##h1h, qa1h, z);                                \
    sB1 = MFMA32(P##l1h, qa1h, sB1);                                    \
    sB1 = MFMA32(P##h1h, qa1l, sB1);                                    \
    f32x4 p0, p1;                                                       \
    _Pragma("unroll")                                                   \
    for (int r = 0; r < 4; r++) {                                       \
        p0[r] = EXP2F(fmaf(sA0[r] + sB0[r], SCALE_LOG2E, m0[r] ? 0.f : -1e9f)); \
        p1[r] = EXP2F(fmaf(sA1[r] + sB1[r], SCALE_LOG2E, m1[r] ? 0.f : -1e9f)); \
        lsum += p0[r] + p1[r];                                          \
    }                                                                   \
    short8 pa = pk8(p0, p1);                                            \
    acc0 = MFMA32(pa, Vv0, acc0);                                       \
    acc1 = MFMA32(pa, Vv1, acc1);                                       \
    acc2 = MFMA32(pa, Vv2, acc2);                                       \
    acc3 = MFMA32(pa, Vv3, acc3);                                       \
    float* arow = attn + (size_t)(b * SQL + qbase + l15) * SKL + (kb) + quad * 4; \
    *(f32x4*)arow        = p0;                                          \
    *(f32x4*)(arow + 16) = p1;                                          \
}

// Single-sweep fused attention: block = 16 q-rows, 4 waves x 512-key quarters.
// Swapped QK keeps P lane-local. PV accumulates UNNORMALIZED; out scaled by
// 1/sum in epilogue; attn holds P' (norm kernel rescales it afterward).
// 2x-unrolled pipeline: next step's 8 K loads (set B) are in flight while
// STEP(A) computes. launch_bounds(256,2) -> VGPR cap 256 so the ~160-reg
// schedule fits and the compiler cannot serialize the loads (round-4 failure
// mode: VGPR=60 forced load->wait->use chains, ~10K cy exposed lat/iter).
__global__ __launch_bounds__(256, 2)
void attn_fwd(const short* __restrict__ ws, const int* __restrict__ mask,
              float* __restrict__ out, float* __restrict__ attn)
{
    __shared__ __align__(16) char smem[16384 + 256];
    f32x4* s_acc = (f32x4*)smem;                 // vt-major: [vt][w*64+lane] (16 KB)
    float* s_red = (float*)(smem + 16384);       // 4 waves x 16 row-sums

    const int tid  = threadIdx.x;
    const int w    = tid >> 6;                   // wave = k-quarter
    const int lane = tid & 63;
    const int l15  = tid & 15;
    const int quad = (tid & 63) >> 4;

    // bijective XCD swizzle: 2048 blocks, 256-block chunks per XCD
    const int bid = blockIdx.x;
    const int swz = (bid & 7) * ((NB * SQL / 16) >> 3) + (bid >> 3);
    const int b     = swz >> 7;
    const int qbase = (swz & 127) * 16;

    const int k0 = w * (SKL / 4);

    const short* qhi = ws + (size_t)(b * SQL + qbase) * DKL;
    const short* qlo = qhi + (size_t)NE;
    const short* khi = ws + (size_t)2 * NE + (size_t)b * SKL * DKL;
    const short* klo = khi + (size_t)NE;
    const short* vtg = ws + (size_t)4 * NE + (size_t)b * DVL * SKL;
    const int*   mk  = mask + b * SKL;

    // Q fragments (B-operand of swapped QK: lane l15 = q, quad = d-chunk)
    short8 qa0h = *(const short8*)(qhi + (size_t)l15 * DKL + quad * 8);
    short8 qa1h = *(const short8*)(qhi + (size_t)l15 * DKL + 32 + quad * 8);
    short8 qa0l = *(const short8*)(qlo + (size_t)l15 * DKL + quad * 8);
    short8 qa1l = *(const short8*)(qlo + (size_t)l15 * DKL + 32 + quad * 8);

    f32x4 acc0 = {0.f,0.f,0.f,0.f}, acc1 = acc0, acc2 = acc0, acc3 = acc0;
    float lsum = 0.f;

    short8 Ah0l, Ah0h, Ah1l, Ah1h, Al0l, Al0h, Al1l, Al1h;
    short8 Bh0l, Bh0h, Bh1l, Bh1h, Bl0l, Bl0h, Bl1l, Bl1h;
    short8 Vv0, Vv1, Vv2, Vv3;

    LOADK(A, k0);
    for (int it = 0; it < 8; ++it) {
        const int kb0 = k0 + it * 64;
        LOADV(kb0);
        LOADK(B, kb0 + 32);          // in flight during STEP(A)
        STEP(A, kb0);
        LOADV(kb0 + 32);
        const int kbn = (it < 7) ? kb0 + 64 : k0;   // harmless reload on last
        LOADK(A, kbn);               // in flight during STEP(B)
        STEP(B, kb0 + 32);
    }

    // ---------- reduce denominators across the 4 k-quarter waves ----------
    lsum += __shfl_xor(lsum, 16, 64);
    lsum += __shfl_xor(lsum, 32, 64);
    if (lane < 16) s_red[w * 16 + l15] = lsum;
    __syncthreads();

    // ---------- combine partial P·V across waves; scale by 1/sum ----------
    s_acc[0 * 256 + w * 64 + lane] = acc0;
    s_acc[1 * 256 + w * 64 + lane] = acc1;
    s_acc[2 * 256 + w * 64 + lane] = acc2;
    s_acc[3 * 256 + w * 64 + lane] = acc3;
    __syncthreads();

    f32x4 t_ = s_acc[w * 256 + 0 * 64 + lane];
    #pragma unroll
    for (int wp = 1; wp < 4; wp++) {
        f32x4 u = s_acc[w * 256 + wp * 64 + lane];
        #pragma unroll
        for (int r = 0; r < 4; r++) t_[r] += u[r];
    }
    #pragma unroll
    for (int r = 0; r < 4; r++) {
        int rr = quad * 4 + r;
        float tt = s_red[rr] + s_red[16 + rr] + s_red[32 + rr] + s_red[48 + rr];
        out[(size_t)(b * SQL + qbase + rr) * DVL + w * 16 + l15] = t_[r] / tt;
    }
}

// ---------- norm: attn[row] /= sum(attn[row]), recomputing the sum ----------
// One block per row; masked entries are exactly 0 (exp2 underflow) so the
// recomputed sum equals the softmax denominator. No side buffer needed.
__global__ __launch_bounds__(256)
void norm(float* __restrict__ attn)
{
    __shared__ float sw[4];
    const int row = blockIdx.x;                  // 0 .. NB*SQL-1
    float* p = attn + (size_t)row * SKL + threadIdx.x * 8;
    f32x4 x0 = *(const f32x4*)p;
    f32x4 x1 = *(const f32x4*)(p + 4);
    float s = (x0[0] + x0[1]) + (x0[2] + x0[3])
            + (x1[0] + x1[1]) + (x1[2] + x1[3]);
    #pragma unroll
    for (int off = 1; off < 64; off <<= 1) s += __shfl_xor(s, off, 64);
    if ((threadIdx.x & 63) == 0) sw[threadIdx.x >> 6] = s;
    __syncthreads();
    const float inv = 1.0f / ((sw[0] + sw[1]) + (sw[2] + sw[3]));
    #pragma unroll
    for (int r = 0; r < 4; r++) { x0[r] *= inv; x1[r] *= inv; }
    *(f32x4*)p       = x0;
    *(f32x4*)(p + 4) = x1;
}

extern "C" void kernel_launch(void* const* d_in, const int* in_sizes, int n_in,
                              void* d_out, int out_size, void* d_ws, size_t ws_size,
                              hipStream_t stream) {
    const float* Q    = (const float*)d_in[0];
    const float* K    = (const float*)d_in[1];
    const float* V    = (const float*)d_in[2];
    const int*   mask = (const int*)d_in[3];
    float* out  = (float*)d_out;
    float* attn = out + (size_t)NB * SQL * DVL;  // tuple order: (output, attn)
    short* ws   = (short*)d_ws;                  // 5*NE shorts = 20 MB (unchanged)

    prep<<<dim3(NE / (256 * 4)), dim3(256), 0, stream>>>(Q, K, ws);
    vtrans<<<dim3(NB * (SKL / 64)), dim3(256), 0, stream>>>(V, ws + (size_t)4 * NE);
    attn_fwd<<<dim3(NB * (SQL / 16)), dim3(256), 0, stream>>>(ws, mask, out, attn);
    norm<<<dim3(NB * SQL), dim3(256), 0, stream>>>(attn);
}